// Round 2
// baseline (355.772 us; speedup 1.0000x reference)
//
#include <hip/hip_runtime.h>
#include <stdint.h>

#define B_ 4
#define S_ 2048
#define D_ 1024
#define H_ 16
#define A_ 64
#define M_ (B_*S_)    // 8192
#define BH_ (B_*H_)   // 64

typedef _Float16 f16x8 __attribute__((ext_vector_type(8)));
typedef float    f32x4 __attribute__((ext_vector_type(4)));

__device__ __forceinline__ uint32_t f2h(float f) {
    _Float16 h = (_Float16)f;                      // RNE
    return (uint32_t)__builtin_bit_cast(uint16_t, h);
}

// XOR swizzle for [R][64]-f16 LDS tiles (row stride 128 B): permutes 16B slots
// within a row by row&7 -> ds_read_b128 across rows becomes ~2-way (free).
__device__ __forceinline__ int swz(int row, int col) {
    return (row * 64 + col) ^ ((row & 7) << 3);
}

// ---------------------------------------------------------------- prep: W -> Wt[p][h][a][d] f16
__global__ __launch_bounds__(256) void prep_w(
    const float* __restrict__ Wq, const float* __restrict__ Wk, const float* __restrict__ Wv,
    uint16_t* __restrict__ Wt)
{
    __shared__ float tile[64][65];
    const int dt = blockIdx.x, h = blockIdx.y, p = blockIdx.z;
    const float* W = (p == 0) ? Wq : (p == 1) ? Wk : Wv;
    const float* src = W + (h * D_ + dt * 64) * A_;   // [64 d][64 a]
    const int t = threadIdx.x;
    const int r0 = t >> 4, c4 = (t & 15) * 4;
    #pragma unroll
    for (int i = 0; i < 4; i++) {
        int r = r0 + i * 16;
        float4 x = *(const float4*)(src + r * A_ + c4);
        tile[r][c4] = x.x; tile[r][c4 + 1] = x.y; tile[r][c4 + 2] = x.z; tile[r][c4 + 3] = x.w;
    }
    __syncthreads();
    uint16_t* dst = Wt + (p * H_ + h) * (A_ * D_) + dt * 64;
    #pragma unroll
    for (int i = 0; i < 4; i++) {
        int a = r0 + i * 16;
        int d4 = (t & 15) * 4;
        uint2 o2;
        o2.x = f2h(tile[d4][a])     | (f2h(tile[d4 + 1][a]) << 16);
        o2.y = f2h(tile[d4 + 2][a]) | (f2h(tile[d4 + 3][a]) << 16);
        *(uint2*)(dst + a * D_ + d4) = o2;
    }
}

// ---------------------------------------------------------------- prep: q/k/v f32 -> f16
__global__ __launch_bounds__(256) void prep_qkv(
    const float* __restrict__ q, const float* __restrict__ k, const float* __restrict__ v,
    uint16_t* __restrict__ qb, uint16_t* __restrict__ kb, uint16_t* __restrict__ vb)
{
    const int gi = blockIdx.x * 256 + threadIdx.x;
    const int NT = M_ * D_ / 8;
    const float* src; uint16_t* dst; int idx;
    if (gi < NT)          { src = q; dst = qb; idx = gi; }
    else if (gi < 2 * NT) { src = k; dst = kb; idx = gi - NT; }
    else                  { src = v; dst = vb; idx = gi - 2 * NT; }
    const int off = idx * 8;
    float4 x0 = *(const float4*)(src + off);
    float4 x1 = *(const float4*)(src + off + 4);
    uint4 o;
    o.x = f2h(x0.x) | (f2h(x0.y) << 16);
    o.y = f2h(x0.z) | (f2h(x0.w) << 16);
    o.z = f2h(x1.x) | (f2h(x1.y) << 16);
    o.w = f2h(x1.z) | (f2h(x1.w) << 16);
    *(uint4*)(dst + off) = o;
}

// ---------------------------------------------------------------- projection GEMM
// block: 256 thr (4 waves), tile M=128 x N=64 (one head), K-step 64.
// out: p<2 -> qh/kh [BH][S][A] f16 ; p==2 -> vhT [BH][A][S] f16 (transposed for PV).
__global__ __launch_bounds__(256) void proj_kernel(
    const float* __restrict__ q, const float* __restrict__ k, const float* __restrict__ v,
    const uint16_t* __restrict__ qb, const uint16_t* __restrict__ kb, const uint16_t* __restrict__ vb,
    const uint16_t* __restrict__ Wt,
    const float* __restrict__ bq, const float* __restrict__ bk, const float* __restrict__ bv,
    uint16_t* __restrict__ qh, uint16_t* __restrict__ kh, uint16_t* __restrict__ vhT,
    int preconv)
{
    __shared__ __align__(16) uint16_t As[128 * 64];
    __shared__ __align__(16) uint16_t Bs[64 * 64];
    const int p = blockIdx.z, h = blockIdx.x, mt = blockIdx.y;
    const int t = threadIdx.x, lane = t & 63, w = t >> 6;
    const int lr = lane & 15, lg = lane >> 4;
    const int Mbase = mt * 128;
    const float*    Af = (p == 0) ? q  : (p == 1) ? k  : v;
    const uint16_t* Ab = (p == 0) ? qb : (p == 1) ? kb : vb;
    const uint16_t* Wp = Wt + (p * H_ + h) * (A_ * D_);
    const float* bias = ((p == 0) ? bq : (p == 1) ? bk : bv) + h * A_;

    f32x4 acc[2][4] = {};

    for (int kk = 0; kk < D_; kk += 64) {
        #pragma unroll
        for (int i = 0; i < 4; i++) {
            int flat = t * 8 + i * 2048;
            int row = flat >> 6, col = flat & 63;
            uint4 val;
            if (preconv) {
                val = *(const uint4*)(Ab + (Mbase + row) * D_ + kk + col);
            } else {
                const float* sp = Af + (Mbase + row) * D_ + kk + col;
                float4 x0 = *(const float4*)sp;
                float4 x1 = *(const float4*)(sp + 4);
                val.x = f2h(x0.x) | (f2h(x0.y) << 16);
                val.y = f2h(x0.z) | (f2h(x0.w) << 16);
                val.z = f2h(x1.x) | (f2h(x1.y) << 16);
                val.w = f2h(x1.z) | (f2h(x1.w) << 16);
            }
            *(uint4*)(As + swz(row, col)) = val;
        }
        #pragma unroll
        for (int i = 0; i < 2; i++) {
            int flat = t * 8 + i * 2048;
            int row = flat >> 6, col = flat & 63;
            uint4 val = *(const uint4*)(Wp + row * D_ + kk + col);
            *(uint4*)(Bs + swz(row, col)) = val;
        }
        __syncthreads();
        #pragma unroll
        for (int kb = 0; kb < 2; kb++) {
            f16x8 af[2], bfr[4];
            #pragma unroll
            for (int mb = 0; mb < 2; mb++)
                af[mb] = *(const f16x8*)(As + swz(w * 32 + mb * 16 + lr, kb * 32 + 8 * lg));
            #pragma unroll
            for (int nb = 0; nb < 4; nb++)
                bfr[nb] = *(const f16x8*)(Bs + swz(nb * 16 + lr, kb * 32 + 8 * lg));
            #pragma unroll
            for (int mb = 0; mb < 2; mb++) {
                #pragma unroll
                for (int nb = 0; nb < 4; nb++)
                    acc[mb][nb] = __builtin_amdgcn_mfma_f32_16x16x32_f16(af[mb], bfr[nb], acc[mb][nb], 0, 0, 0);
            }
        }
        __syncthreads();
    }

    const int b = Mbase >> 11;           // S_=2048 rows per batch
    const int bh = b * H_ + h;
    const int sbase = Mbase & (S_ - 1);
    #pragma unroll
    for (int mb = 0; mb < 2; mb++) {
        #pragma unroll
        for (int nb = 0; nb < 4; nb++) {
            const int a = nb * 16 + lr;
            const float bia = bias[a];
            const int s0 = sbase + w * 32 + mb * 16 + 4 * lg;
            if (p < 2) {
                uint16_t* o = (p == 0) ? qh : kh;
                #pragma unroll
                for (int r = 0; r < 4; r++)
                    o[(bh * S_ + s0 + r) * A_ + a] = (uint16_t)f2h(acc[mb][nb][r] + bia);
            } else {
                uint2 pk2;
                pk2.x = f2h(acc[mb][nb][0] + bia) | (f2h(acc[mb][nb][1] + bia) << 16);
                pk2.y = f2h(acc[mb][nb][2] + bia) | (f2h(acc[mb][nb][3] + bia) << 16);
                *(uint2*)(vhT + (bh * A_ + a) * S_ + s0) = pk2;
            }
        }
    }
}

// ---------------------------------------------------------------- flash attention
// block: 256 thr (4 waves), 64 q-rows (16/wave), KV-tiles of 64, online softmax f32.
__global__ __launch_bounds__(256) void flash_kernel(
    const uint16_t* __restrict__ qh, const uint16_t* __restrict__ kh,
    const uint16_t* __restrict__ vhT, float* __restrict__ out)
{
    __shared__ __align__(16) uint16_t Ks[64 * 64];
    __shared__ __align__(16) uint16_t Vs[64 * 64];   // [a][kcol] (from vhT)
    __shared__ __align__(16) uint16_t Ps[4][16 * 64];
    const int t = threadIdx.x, lane = t & 63, w = t >> 6;
    const int lr = lane & 15, lg = lane >> 4;
    const int qt = blockIdx.x, bh = blockIdx.y;
    const int b = bh >> 4, h = bh & (H_ - 1);
    const int qrow = qt * 64 + w * 16 + lr;

    f16x8 qf[2];
    {
        const uint16_t* qp = qh + (bh * S_ + qrow) * A_;
        qf[0] = *(const f16x8*)(qp + 8 * lg);
        qf[1] = *(const f16x8*)(qp + 32 + 8 * lg);
    }
    float m_r[4], l_r[4];
    #pragma unroll
    for (int r = 0; r < 4; r++) { m_r[r] = -3.0e38f; l_r[r] = 0.0f; }
    f32x4 oacc[4] = {};
    uint16_t* Pw = Ps[w];

    for (int kt = 0; kt < S_ / 64; kt++) {
        const int kbase = kt * 64;
        #pragma unroll
        for (int i = 0; i < 2; i++) {
            int flat = t * 8 + i * 2048;
            int row = flat >> 6, col = flat & 63;
            uint4 kv = *(const uint4*)(kh + (bh * S_ + kbase + row) * A_ + col);
            *(uint4*)(Ks + swz(row, col)) = kv;
            uint4 vv = *(const uint4*)(vhT + (bh * A_ + row) * S_ + kbase + col);
            *(uint4*)(Vs + swz(row, col)) = vv;
        }
        __syncthreads();

        f32x4 sacc[4] = {};
        #pragma unroll
        for (int kb = 0; kb < 2; kb++) {
            #pragma unroll
            for (int nb = 0; nb < 4; nb++) {
                f16x8 kf = *(const f16x8*)(Ks + swz(nb * 16 + lr, kb * 32 + 8 * lg));
                sacc[nb] = __builtin_amdgcn_mfma_f32_16x16x32_f16(qf[kb], kf, sacc[nb], 0, 0, 0);
            }
        }

        float pv_[4][4];
        #pragma unroll
        for (int r = 0; r < 4; r++) {
            float tm = fmaxf(fmaxf(sacc[0][r], sacc[1][r]), fmaxf(sacc[2][r], sacc[3][r]));
            #pragma unroll
            for (int d = 1; d < 16; d <<= 1) tm = fmaxf(tm, __shfl_xor(tm, d));
            float mn = fmaxf(m_r[r], tm);
            float sc = __expf(m_r[r] - mn);   // first iter: exp(-inf)=0
            float rs = 0.0f;
            #pragma unroll
            for (int nb = 0; nb < 4; nb++) { float e = __expf(sacc[nb][r] - mn); pv_[nb][r] = e; rs += e; }
            #pragma unroll
            for (int d = 1; d < 16; d <<= 1) rs += __shfl_xor(rs, d);
            l_r[r] = l_r[r] * sc + rs;
            m_r[r] = mn;
            #pragma unroll
            for (int nb = 0; nb < 4; nb++) oacc[nb][r] *= sc;
        }

        // C-layout -> A-layout via per-wave LDS tile
        #pragma unroll
        for (int nb = 0; nb < 4; nb++) {
            #pragma unroll
            for (int r = 0; r < 4; r++)
                Pw[swz(4 * lg + r, nb * 16 + lr)] = (uint16_t)f2h(pv_[nb][r]);
        }
        asm volatile("s_waitcnt lgkmcnt(0)" ::: "memory");

        #pragma unroll
        for (int kb = 0; kb < 2; kb++) {
            f16x8 pf = *(const f16x8*)(Pw + swz(lr, kb * 32 + 8 * lg));
            #pragma unroll
            for (int nb = 0; nb < 4; nb++) {
                f16x8 vf = *(const f16x8*)(Vs + swz(nb * 16 + lr, kb * 32 + 8 * lg));
                oacc[nb] = __builtin_amdgcn_mfma_f32_16x16x32_f16(pf, vf, oacc[nb], 0, 0, 0);
            }
        }
        __syncthreads();
    }

    #pragma unroll
    for (int nb = 0; nb < 4; nb++) {
        const int a = nb * 16 + lr;
        #pragma unroll
        for (int r = 0; r < 4; r++) {
            const int s = qt * 64 + w * 16 + 4 * lg + r;
            out[(b * S_ + s) * (H_ * A_) + h * A_ + a] = oacc[nb][r] / l_r[r];
        }
    }
}

// ----------------------------------------------------------------
extern "C" void kernel_launch(void* const* d_in, const int* in_sizes, int n_in,
                              void* d_out, int out_size, void* d_ws, size_t ws_size,
                              hipStream_t stream)
{
    const float* q  = (const float*)d_in[0];
    const float* k  = (const float*)d_in[1];
    const float* v  = (const float*)d_in[2];
    const float* Wq = (const float*)d_in[3];
    const float* bq = (const float*)d_in[4];
    const float* Wk = (const float*)d_in[5];
    const float* bk = (const float*)d_in[6];
    const float* Wv = (const float*)d_in[7];
    const float* bv = (const float*)d_in[8];
    float* out = (float*)d_out;

    uint8_t* ws = (uint8_t*)d_ws;
    const size_t SZ_H  = (size_t)BH_ * S_ * A_ * 2;     // 16 MB each
    const size_t SZ_WT = (size_t)3 * H_ * A_ * D_ * 2;  // 6 MB
    const size_t SZ_AB = (size_t)M_ * D_ * 2;           // 16 MB each
    uint16_t* qh  = (uint16_t*)(ws);
    uint16_t* kh  = (uint16_t*)(ws + SZ_H);
    uint16_t* vhT = (uint16_t*)(ws + 2 * SZ_H);
    uint16_t* Wt  = (uint16_t*)(ws + 3 * SZ_H);
    uint16_t* qb  = (uint16_t*)(ws + 3 * SZ_H + SZ_WT);
    uint16_t* kb  = (uint16_t*)(ws + 3 * SZ_H + SZ_WT + SZ_AB);
    uint16_t* vb  = (uint16_t*)(ws + 3 * SZ_H + SZ_WT + 2 * SZ_AB);
    const int preconv = (ws_size >= 3 * SZ_H + SZ_WT + 3 * SZ_AB) ? 1 : 0;

    prep_w<<<dim3(16, H_, 3), 256, 0, stream>>>(Wq, Wk, Wv, Wt);
    if (preconv)
        prep_qkv<<<dim3(3 * M_ * D_ / 8 / 256), 256, 0, stream>>>(q, k, v, qb, kb, vb);
    proj_kernel<<<dim3(H_, M_ / 128, 3), 256, 0, stream>>>(q, k, v, qb, kb, vb, Wt,
                                                           bq, bk, bv, qh, kh, vhT, preconv);
    flash_kernel<<<dim3(S_ / 64, BH_), 256, 0, stream>>>(qh, kh, vhT, out);
}

// Round 3
// 315.013 us; speedup vs baseline: 1.1294x; 1.1294x over previous
//
#include <hip/hip_runtime.h>
#include <stdint.h>

#define B_ 4
#define S_ 2048
#define D_ 1024
#define H_ 16
#define A_ 64
#define M_ (B_*S_)    // 8192
#define BH_ (B_*H_)   // 64

typedef _Float16 f16x8 __attribute__((ext_vector_type(8)));
typedef float    f32x4 __attribute__((ext_vector_type(4)));

__device__ __forceinline__ uint32_t f2h(float f) {
    _Float16 h = (_Float16)f;                      // RNE
    return (uint32_t)__builtin_bit_cast(uint16_t, h);
}

// XOR swizzle for [R][64]-f16 LDS tiles (row stride 128 B): permutes 16B slots
// within a row by row&7 -> ds_read_b128 across rows becomes ~2-way (free).
__device__ __forceinline__ int swz(int row, int col) {
    return (row * 64 + col) ^ ((row & 7) << 3);
}

// ---------------------------------------------------------------- prep: W -> Wt[p][h][a][d] f16
__global__ __launch_bounds__(256) void prep_w(
    const float* __restrict__ Wq, const float* __restrict__ Wk, const float* __restrict__ Wv,
    uint16_t* __restrict__ Wt)
{
    __shared__ float tile[64][65];
    const int dt = blockIdx.x, h = blockIdx.y, p = blockIdx.z;
    const float* W = (p == 0) ? Wq : (p == 1) ? Wk : Wv;
    const float* src = W + (h * D_ + dt * 64) * A_;   // [64 d][64 a]
    const int t = threadIdx.x;
    const int r0 = t >> 4, c4 = (t & 15) * 4;
    #pragma unroll
    for (int i = 0; i < 4; i++) {
        int r = r0 + i * 16;
        float4 x = *(const float4*)(src + r * A_ + c4);
        tile[r][c4] = x.x; tile[r][c4 + 1] = x.y; tile[r][c4 + 2] = x.z; tile[r][c4 + 3] = x.w;
    }
    __syncthreads();
    uint16_t* dst = Wt + (p * H_ + h) * (A_ * D_) + dt * 64;
    #pragma unroll
    for (int i = 0; i < 4; i++) {
        int a = r0 + i * 16;
        int d4 = (t & 15) * 4;
        uint2 o2;
        o2.x = f2h(tile[d4][a])     | (f2h(tile[d4 + 1][a]) << 16);
        o2.y = f2h(tile[d4 + 2][a]) | (f2h(tile[d4 + 3][a]) << 16);
        *(uint2*)(dst + a * D_ + d4) = o2;
    }
}

// ---------------------------------------------------------------- prep: q/k/v f32 -> f16
__global__ __launch_bounds__(256) void prep_qkv(
    const float* __restrict__ q, const float* __restrict__ k, const float* __restrict__ v,
    uint16_t* __restrict__ qb, uint16_t* __restrict__ kb, uint16_t* __restrict__ vb)
{
    const int gi = blockIdx.x * 256 + threadIdx.x;
    const int NT = M_ * D_ / 8;
    const float* src; uint16_t* dst; int idx;
    if (gi < NT)          { src = q; dst = qb; idx = gi; }
    else if (gi < 2 * NT) { src = k; dst = kb; idx = gi - NT; }
    else                  { src = v; dst = vb; idx = gi - 2 * NT; }
    const int off = idx * 8;
    float4 x0 = *(const float4*)(src + off);
    float4 x1 = *(const float4*)(src + off + 4);
    uint4 o;
    o.x = f2h(x0.x) | (f2h(x0.y) << 16);
    o.y = f2h(x0.z) | (f2h(x0.w) << 16);
    o.z = f2h(x1.x) | (f2h(x1.y) << 16);
    o.w = f2h(x1.z) | (f2h(x1.w) << 16);
    *(uint4*)(dst + off) = o;
}

// ---------------------------------------------------------------- projection GEMM
// block: 256 thr (4 waves), tile M=128 x N=64 (one head), K-step 64.
// out: p<2 -> qh/kh [BH][S][A] f16 ; p==2 -> vhT [BH][A][S] f16 (transposed for PV).
__global__ __launch_bounds__(256) void proj_kernel(
    const float* __restrict__ q, const float* __restrict__ k, const float* __restrict__ v,
    const uint16_t* __restrict__ qb, const uint16_t* __restrict__ kb, const uint16_t* __restrict__ vb,
    const uint16_t* __restrict__ Wt,
    const float* __restrict__ bq, const float* __restrict__ bk, const float* __restrict__ bv,
    uint16_t* __restrict__ qh, uint16_t* __restrict__ kh, uint16_t* __restrict__ vhT,
    int preconv)
{
    __shared__ __align__(16) uint16_t As[128 * 64];
    __shared__ __align__(16) uint16_t Bs[64 * 64];
    const int p = blockIdx.z, h = blockIdx.x, mt = blockIdx.y;
    const int t = threadIdx.x, lane = t & 63, w = t >> 6;
    const int lr = lane & 15, lg = lane >> 4;
    const int Mbase = mt * 128;
    const float*    Af = (p == 0) ? q  : (p == 1) ? k  : v;
    const uint16_t* Ab = (p == 0) ? qb : (p == 1) ? kb : vb;
    const uint16_t* Wp = Wt + (p * H_ + h) * (A_ * D_);
    const float* bias = ((p == 0) ? bq : (p == 1) ? bk : bv) + h * A_;

    f32x4 acc[2][4] = {};

    for (int kk = 0; kk < D_; kk += 64) {
        #pragma unroll
        for (int i = 0; i < 4; i++) {
            int flat = t * 8 + i * 2048;
            int row = flat >> 6, col = flat & 63;
            uint4 val;
            if (preconv) {
                val = *(const uint4*)(Ab + (Mbase + row) * D_ + kk + col);
            } else {
                const float* sp = Af + (Mbase + row) * D_ + kk + col;
                float4 x0 = *(const float4*)sp;
                float4 x1 = *(const float4*)(sp + 4);
                val.x = f2h(x0.x) | (f2h(x0.y) << 16);
                val.y = f2h(x0.z) | (f2h(x0.w) << 16);
                val.z = f2h(x1.x) | (f2h(x1.y) << 16);
                val.w = f2h(x1.z) | (f2h(x1.w) << 16);
            }
            *(uint4*)(As + swz(row, col)) = val;
        }
        #pragma unroll
        for (int i = 0; i < 2; i++) {
            int flat = t * 8 + i * 2048;
            int row = flat >> 6, col = flat & 63;
            uint4 val = *(const uint4*)(Wp + row * D_ + kk + col);
            *(uint4*)(Bs + swz(row, col)) = val;
        }
        __syncthreads();
        #pragma unroll
        for (int kb = 0; kb < 2; kb++) {
            f16x8 af[2], bfr[4];
            #pragma unroll
            for (int mb = 0; mb < 2; mb++)
                af[mb] = *(const f16x8*)(As + swz(w * 32 + mb * 16 + lr, kb * 32 + 8 * lg));
            #pragma unroll
            for (int nb = 0; nb < 4; nb++)
                bfr[nb] = *(const f16x8*)(Bs + swz(nb * 16 + lr, kb * 32 + 8 * lg));
            #pragma unroll
            for (int mb = 0; mb < 2; mb++) {
                #pragma unroll
                for (int nb = 0; nb < 4; nb++)
                    acc[mb][nb] = __builtin_amdgcn_mfma_f32_16x16x32_f16(af[mb], bfr[nb], acc[mb][nb], 0, 0, 0);
            }
        }
        __syncthreads();
    }

    const int b = Mbase >> 11;           // S_=2048 rows per batch
    const int bh = b * H_ + h;
    const int sbase = Mbase & (S_ - 1);
    #pragma unroll
    for (int mb = 0; mb < 2; mb++) {
        #pragma unroll
        for (int nb = 0; nb < 4; nb++) {
            const int a = nb * 16 + lr;
            const float bia = bias[a];
            const int s0 = sbase + w * 32 + mb * 16 + 4 * lg;
            if (p < 2) {
                uint16_t* o = (p == 0) ? qh : kh;
                #pragma unroll
                for (int r = 0; r < 4; r++)
                    o[(bh * S_ + s0 + r) * A_ + a] = (uint16_t)f2h(acc[mb][nb][r] + bia);
            } else {
                uint2 pk2;
                pk2.x = f2h(acc[mb][nb][0] + bia) | (f2h(acc[mb][nb][1] + bia) << 16);
                pk2.y = f2h(acc[mb][nb][2] + bia) | (f2h(acc[mb][nb][3] + bia) << 16);
                *(uint2*)(vhT + (bh * A_ + a) * S_ + s0) = pk2;
            }
        }
    }
}

// ---------------------------------------------------------------- flash attention
// block: 256 thr (4 waves), 64 q-rows (16/wave), KV-tiles of 64.
// Double-buffered K/V staged via global_load_lds (pre-swizzled source),
// defer-max (THR=8) online softmax, deferred l-reduction, 1 barrier/tile.
__global__ __launch_bounds__(256) void flash_kernel(
    const uint16_t* __restrict__ qh, const uint16_t* __restrict__ kh,
    const uint16_t* __restrict__ vhT, float* __restrict__ out)
{
    __shared__ __align__(16) uint16_t Ks[2][4096];
    __shared__ __align__(16) uint16_t Vs[2][4096];
    __shared__ __align__(16) uint16_t Ps[4][1024];
    const int t = threadIdx.x, lane = t & 63, w = t >> 6;
    const int lr = lane & 15, lg = lane >> 4;
    const int qt = blockIdx.x, bh = blockIdx.y;
    const int b = bh >> 4, h = bh & (H_ - 1);
    const int qrow = qt * 64 + w * 16 + lr;

    f16x8 qf[2];
    {
        const uint16_t* qp = qh + (size_t)(bh * S_ + qrow) * A_;
        qf[0] = *(const f16x8*)(qp + 8 * lg);
        qf[1] = *(const f16x8*)(qp + 32 + 8 * lg);
    }

    // Staging: linear LDS dest (global_load_lds writes base + lane*16B);
    // swizzle is applied by pre-swizzling the global source column.
    // Round i covers rows [32*i, 32*i+32); (row+32)&7 == row&7, so one scol works.
    const int row0 = t >> 3;           // (t*8)>>6
    const int col0 = (t * 8) & 63;
    const int scol = col0 ^ ((row0 & 7) << 3);
    const uint16_t* kg = kh  + (size_t)(bh * S_ + row0) * A_ + scol;   // advances 64 rows/tile
    const uint16_t* vg = vhT + (size_t)(bh * A_ + row0) * S_ + scol;   // advances 64 cols/tile

    float m_r[4], l_r[4];
    #pragma unroll
    for (int r = 0; r < 4; r++) { m_r[r] = -3.0e38f; l_r[r] = 0.0f; }
    f32x4 oacc[4] = {};
    uint16_t* Pw = Ps[w];

    #define STAGE(buf, kt_) do {                                                          \
        const uint16_t* kp_ = kg + (size_t)(kt_) * (64 * A_);                             \
        const uint16_t* vp_ = vg + (kt_) * 64;                                            \
        __builtin_amdgcn_global_load_lds(kp_,           &Ks[buf][w * 512],        16, 0, 0); \
        __builtin_amdgcn_global_load_lds(kp_ + 32 * A_, &Ks[buf][2048 + w * 512], 16, 0, 0); \
        __builtin_amdgcn_global_load_lds(vp_,           &Vs[buf][w * 512],        16, 0, 0); \
        __builtin_amdgcn_global_load_lds(vp_ + 32 * S_, &Vs[buf][2048 + w * 512], 16, 0, 0); \
    } while (0)

    STAGE(0, 0);
    __syncthreads();   // drains vmcnt: buf0 ready

    for (int kt = 0; kt < S_ / 64; kt++) {
        const int cur = kt & 1;
        if (kt + 1 < S_ / 64) STAGE(cur ^ 1, kt + 1);

        // QK^T: sacc[nb][r] = score(q = 4*lg + r, kv = nb*16 + lr)
        f32x4 sacc[4] = {};
        #pragma unroll
        for (int kb = 0; kb < 2; kb++) {
            #pragma unroll
            for (int nb = 0; nb < 4; nb++) {
                f16x8 kf = *(const f16x8*)(&Ks[cur][0] + swz(nb * 16 + lr, kb * 32 + 8 * lg));
                sacc[nb] = __builtin_amdgcn_mfma_f32_16x16x32_f16(qf[kb], kf, sacc[nb], 0, 0, 0);
            }
        }

        // per-row tile max (group-uniform after reduce)
        float tm[4];
        #pragma unroll
        for (int r = 0; r < 4; r++) {
            float t0 = fmaxf(fmaxf(sacc[0][r], sacc[1][r]), fmaxf(sacc[2][r], sacc[3][r]));
            #pragma unroll
            for (int d = 1; d < 16; d <<= 1) t0 = fmaxf(t0, __shfl_xor(t0, d));
            tm[r] = t0;
        }
        // defer-max: rescale only if some row grew past m+8 (P stays <= e^8 < f16 max)
        bool need = (tm[0] > m_r[0] + 8.0f) || (tm[1] > m_r[1] + 8.0f) ||
                    (tm[2] > m_r[2] + 8.0f) || (tm[3] > m_r[3] + 8.0f);
        if (__any(need)) {
            #pragma unroll
            for (int r = 0; r < 4; r++) {
                float mn = fmaxf(m_r[r], tm[r]);
                float sc = __expf(m_r[r] - mn);
                l_r[r] *= sc;
                #pragma unroll
                for (int nb = 0; nb < 4; nb++) oacc[nb][r] *= sc;
                m_r[r] = mn;
            }
        }

        // P = exp(s - m); l accumulates per-lane partials (reduced once at the end)
        #pragma unroll
        for (int r = 0; r < 4; r++) {
            #pragma unroll
            for (int nb = 0; nb < 4; nb++) {
                float e = __expf(sacc[nb][r] - m_r[r]);
                l_r[r] += e;
                Pw[swz(4 * lg + r, nb * 16 + lr)] = (uint16_t)f2h(e);
            }
        }
        asm volatile("s_waitcnt lgkmcnt(0)" ::: "memory");

        // PV
        #pragma unroll
        for (int kb = 0; kb < 2; kb++) {
            f16x8 pf = *(const f16x8*)(Pw + swz(lr, kb * 32 + 8 * lg));
            #pragma unroll
            for (int nb = 0; nb < 4; nb++) {
                f16x8 vf = *(const f16x8*)(&Vs[cur][0] + swz(nb * 16 + lr, kb * 32 + 8 * lg));
                oacc[nb] = __builtin_amdgcn_mfma_f32_16x16x32_f16(pf, vf, oacc[nb], 0, 0, 0);
            }
        }
        __syncthreads();   // drains vmcnt (next buf ready) + all waves done with cur buf
    }
    #undef STAGE

    // final l reduction across the 16-lane group, then normalize + store
    #pragma unroll
    for (int r = 0; r < 4; r++) {
        float s = l_r[r];
        #pragma unroll
        for (int d = 1; d < 16; d <<= 1) s += __shfl_xor(s, d);
        l_r[r] = s;
    }
    #pragma unroll
    for (int r = 0; r < 4; r++) {
        const float inv = 1.0f / l_r[r];
        const int s = qt * 64 + w * 16 + 4 * lg + r;
        #pragma unroll
        for (int nb = 0; nb < 4; nb++) {
            const int a = nb * 16 + lr;
            out[(size_t)(b * S_ + s) * (H_ * A_) + h * A_ + a] = oacc[nb][r] * inv;
        }
    }
}

// ----------------------------------------------------------------
extern "C" void kernel_launch(void* const* d_in, const int* in_sizes, int n_in,
                              void* d_out, int out_size, void* d_ws, size_t ws_size,
                              hipStream_t stream)
{
    const float* q  = (const float*)d_in[0];
    const float* k  = (const float*)d_in[1];
    const float* v  = (const float*)d_in[2];
    const float* Wq = (const float*)d_in[3];
    const float* bq = (const float*)d_in[4];
    const float* Wk = (const float*)d_in[5];
    const float* bk = (const float*)d_in[6];
    const float* Wv = (const float*)d_in[7];
    const float* bv = (const float*)d_in[8];
    float* out = (float*)d_out;

    uint8_t* ws = (uint8_t*)d_ws;
    const size_t SZ_H  = (size_t)BH_ * S_ * A_ * 2;     // 16 MB each
    const size_t SZ_WT = (size_t)3 * H_ * A_ * D_ * 2;  // 6 MB
    const size_t SZ_AB = (size_t)M_ * D_ * 2;           // 16 MB each
    uint16_t* qh  = (uint16_t*)(ws);
    uint16_t* kh  = (uint16_t*)(ws + SZ_H);
    uint16_t* vhT = (uint16_t*)(ws + 2 * SZ_H);
    uint16_t* Wt  = (uint16_t*)(ws + 3 * SZ_H);
    uint16_t* qb  = (uint16_t*)(ws + 3 * SZ_H + SZ_WT);
    uint16_t* kb  = (uint16_t*)(ws + 3 * SZ_H + SZ_WT + SZ_AB);
    uint16_t* vb  = (uint16_t*)(ws + 3 * SZ_H + SZ_WT + 2 * SZ_AB);
    const int preconv = (ws_size >= 3 * SZ_H + SZ_WT + 3 * SZ_AB) ? 1 : 0;

    prep_w<<<dim3(16, H_, 3), 256, 0, stream>>>(Wq, Wk, Wv, Wt);
    if (preconv)
        prep_qkv<<<dim3(3 * M_ * D_ / 8 / 256), 256, 0, stream>>>(q, k, v, qb, kb, vb);
    proj_kernel<<<dim3(H_, M_ / 128, 3), 256, 0, stream>>>(q, k, v, qb, kb, vb, Wt,
                                                           bq, bk, bv, qh, kh, vhT, preconv);
    flash_kernel<<<dim3(S_ / 64, BH_), 256, 0, stream>>>(qh, kh, vhT, out);
}

// Round 5
// 245.833 us; speedup vs baseline: 1.4472x; 1.2814x over previous
//
#include <hip/hip_runtime.h>
#include <stdint.h>

#define B_ 4
#define S_ 2048
#define D_ 1024
#define H_ 16
#define A_ 64
#define M_ (B_*S_)    // 8192
#define BH_ (B_*H_)   // 64
#define INV_LN2 1.4426950408889634f

typedef _Float16 f16x8 __attribute__((ext_vector_type(8)));
typedef float    f32x4 __attribute__((ext_vector_type(4)));

__device__ __forceinline__ uint32_t f2h(float f) {
    _Float16 h = (_Float16)f;                      // RNE
    return (uint32_t)__builtin_bit_cast(uint16_t, h);
}

__device__ __forceinline__ float exp2f_fast(float x) {
    return __builtin_amdgcn_exp2f(x);              // v_exp_f32: computes 2^x
}

// XOR swizzle for [R][64]-f16 LDS tiles (row stride 128 B)
__device__ __forceinline__ int swz(int row, int col) {
    return (row * 64 + col) ^ ((row & 7) << 3);
}

// ---------------------------------------------------------------- prep: W -> Wt[p][h][a][d] f16
// p==0 (Wq) additionally scaled by 1/ln2 so QK^T scores land in log2 domain.
__global__ __launch_bounds__(256) void prep_w(
    const float* __restrict__ Wq, const float* __restrict__ Wk, const float* __restrict__ Wv,
    uint16_t* __restrict__ Wt)
{
    __shared__ float tile[64][65];
    const int dt = blockIdx.x, h = blockIdx.y, p = blockIdx.z;
    const float* W = (p == 0) ? Wq : (p == 1) ? Wk : Wv;
    const float sc = (p == 0) ? INV_LN2 : 1.0f;
    const float* src = W + (h * D_ + dt * 64) * A_;   // [64 d][64 a]
    const int t = threadIdx.x;
    const int r0 = t >> 4, c4 = (t & 15) * 4;
    #pragma unroll
    for (int i = 0; i < 4; i++) {
        int r = r0 + i * 16;
        float4 x = *(const float4*)(src + r * A_ + c4);
        tile[r][c4] = x.x; tile[r][c4 + 1] = x.y; tile[r][c4 + 2] = x.z; tile[r][c4 + 3] = x.w;
    }
    __syncthreads();
    uint16_t* dst = Wt + (p * H_ + h) * (A_ * D_) + dt * 64;
    #pragma unroll
    for (int i = 0; i < 4; i++) {
        int a = r0 + i * 16;
        int d4 = (t & 15) * 4;
        uint2 o2;
        o2.x = f2h(tile[d4][a] * sc)     | (f2h(tile[d4 + 1][a] * sc) << 16);
        o2.y = f2h(tile[d4 + 2][a] * sc) | (f2h(tile[d4 + 3][a] * sc) << 16);
        *(uint2*)(dst + a * D_ + d4) = o2;
    }
}

// ---------------------------------------------------------------- prep: q/k/v f32 -> f16
__global__ __launch_bounds__(256) void prep_qkv(
    const float* __restrict__ q, const float* __restrict__ k, const float* __restrict__ v,
    uint16_t* __restrict__ qb, uint16_t* __restrict__ kb, uint16_t* __restrict__ vb)
{
    const int gi = blockIdx.x * 256 + threadIdx.x;
    const int NT = M_ * D_ / 8;
    const float* src; uint16_t* dst; int idx;
    if (gi < NT)          { src = q; dst = qb; idx = gi; }
    else if (gi < 2 * NT) { src = k; dst = kb; idx = gi - NT; }
    else                  { src = v; dst = vb; idx = gi - 2 * NT; }
    const int off = idx * 8;
    float4 x0 = *(const float4*)(src + off);
    float4 x1 = *(const float4*)(src + off + 4);
    uint4 o;
    o.x = f2h(x0.x) | (f2h(x0.y) << 16);
    o.y = f2h(x0.z) | (f2h(x0.w) << 16);
    o.z = f2h(x1.x) | (f2h(x1.y) << 16);
    o.w = f2h(x1.z) | (f2h(x1.w) << 16);
    *(uint4*)(dst + off) = o;
}

// ---------------------------------------------------------------- projection GEMM
// out: p==0/1 -> qh/kh [BH][S][A] f16 (qh pre-scaled by 1/ln2);
//      p==2   -> vpv [BH][32 kt][kb][lg][a][8] f16 chunk layout (PV B-fragments).
__global__ __launch_bounds__(256) void proj_kernel(
    const float* __restrict__ q, const float* __restrict__ k, const float* __restrict__ v,
    const uint16_t* __restrict__ qb, const uint16_t* __restrict__ kb, const uint16_t* __restrict__ vb,
    const uint16_t* __restrict__ Wt,
    const float* __restrict__ bq, const float* __restrict__ bk, const float* __restrict__ bv,
    uint16_t* __restrict__ qh, uint16_t* __restrict__ kh, uint16_t* __restrict__ vpv,
    int preconv)
{
    __shared__ __align__(16) uint16_t As[128 * 64];
    __shared__ __align__(16) uint16_t Bs[64 * 64];
    const int p = blockIdx.z, h = blockIdx.x, mt = blockIdx.y;
    const int t = threadIdx.x, lane = t & 63, w = t >> 6;
    const int lr = lane & 15, lg = lane >> 4;
    const int Mbase = mt * 128;
    const float*    Af = (p == 0) ? q  : (p == 1) ? k  : v;
    const uint16_t* Ab = (p == 0) ? qb : (p == 1) ? kb : vb;
    const uint16_t* Wp = Wt + (p * H_ + h) * (A_ * D_);
    const float* bias = ((p == 0) ? bq : (p == 1) ? bk : bv) + h * A_;
    const float bsc = (p == 0) ? INV_LN2 : 1.0f;

    f32x4 acc[2][4] = {};

    for (int kk = 0; kk < D_; kk += 64) {
        #pragma unroll
        for (int i = 0; i < 4; i++) {
            int flat = t * 8 + i * 2048;
            int row = flat >> 6, col = flat & 63;
            uint4 val;
            if (preconv) {
                val = *(const uint4*)(Ab + (Mbase + row) * D_ + kk + col);
            } else {
                const float* sp = Af + (Mbase + row) * D_ + kk + col;
                float4 x0 = *(const float4*)sp;
                float4 x1 = *(const float4*)(sp + 4);
                val.x = f2h(x0.x) | (f2h(x0.y) << 16);
                val.y = f2h(x0.z) | (f2h(x0.w) << 16);
                val.z = f2h(x1.x) | (f2h(x1.y) << 16);
                val.w = f2h(x1.z) | (f2h(x1.w) << 16);
            }
            *(uint4*)(As + swz(row, col)) = val;
        }
        #pragma unroll
        for (int i = 0; i < 2; i++) {
            int flat = t * 8 + i * 2048;
            int row = flat >> 6, col = flat & 63;
            uint4 val = *(const uint4*)(Wp + row * D_ + kk + col);
            *(uint4*)(Bs + swz(row, col)) = val;
        }
        __syncthreads();
        #pragma unroll
        for (int kbi = 0; kbi < 2; kbi++) {
            f16x8 af[2], bfr[4];
            #pragma unroll
            for (int mb = 0; mb < 2; mb++)
                af[mb] = *(const f16x8*)(As + swz(w * 32 + mb * 16 + lr, kbi * 32 + 8 * lg));
            #pragma unroll
            for (int nb = 0; nb < 4; nb++)
                bfr[nb] = *(const f16x8*)(Bs + swz(nb * 16 + lr, kbi * 32 + 8 * lg));
            #pragma unroll
            for (int mb = 0; mb < 2; mb++) {
                #pragma unroll
                for (int nb = 0; nb < 4; nb++)
                    acc[mb][nb] = __builtin_amdgcn_mfma_f32_16x16x32_f16(af[mb], bfr[nb], acc[mb][nb], 0, 0, 0);
            }
        }
        __syncthreads();
    }

    const int b = Mbase >> 11;           // S_=2048 rows per batch
    const int bh = b * H_ + h;
    const int sbase = Mbase & (S_ - 1);
    #pragma unroll
    for (int mb = 0; mb < 2; mb++) {
        #pragma unroll
        for (int nb = 0; nb < 4; nb++) {
            const int a = nb * 16 + lr;
            const float bia = bias[a] * bsc;
            const int s0 = sbase + w * 32 + mb * 16 + 4 * lg;
            if (p < 2) {
                uint16_t* o = (p == 0) ? qh : kh;
                #pragma unroll
                for (int r = 0; r < 4; r++)
                    o[(bh * S_ + s0 + r) * A_ + a] = (uint16_t)f2h(acc[mb][nb][r] + bia);
            } else {
                // chunk layout: [(bh*32+kt)*512 + kb2*256 + lg2*64 + a] chunks of 8 u16
                const int kt2 = s0 >> 6, kv0 = s0 & 63;
                const int kb2 = kv0 >> 5, jhi = (kv0 >> 4) & 1, lg2 = (kv0 >> 2) & 3;
                uint2 pk2;
                pk2.x = f2h(acc[mb][nb][0] + bia) | (f2h(acc[mb][nb][1] + bia) << 16);
                pk2.y = f2h(acc[mb][nb][2] + bia) | (f2h(acc[mb][nb][3] + bia) << 16);
                *(uint2*)(vpv + ((size_t)((bh * 32 + kt2) * 512 + kb2 * 256 + lg2 * 64 + a)) * 8 + 4 * jhi) = pk2;
            }
        }
    }
}

// ---------------------------------------------------------------- flash attention
// Swapped QK^T (A=K, B=Q): each lane owns one q-row; P stays in registers and
// feeds PV's A-fragment directly via the shared k-permutation
// pi(8*lg+j) = 32*kb + 4*lg + (j&3) + 16*(j>>2). V comes pre-chunked from proj.
__global__ __launch_bounds__(256) void flash_kernel(
    const uint16_t* __restrict__ qh, const uint16_t* __restrict__ kh,
    const uint16_t* __restrict__ vpv, float* __restrict__ out)
{
    __shared__ __align__(16) uint16_t Ks[2][4096];
    __shared__ __align__(16) uint16_t Vs[2][4096];
    const int t = threadIdx.x, lane = t & 63, w = t >> 6;
    const int lr = lane & 15, lg = lane >> 4;
    const int qt = blockIdx.x, bh = blockIdx.y;
    const int b = bh >> 4, h = bh & (H_ - 1);

    // Q as B-fragment: lane (lr,lg) holds Q[q = w*16+lr][d = kb*32 + 8*lg + j]
    f16x8 qf[2];
    {
        const uint16_t* qp = qh + (size_t)(bh * S_ + qt * 64 + w * 16 + lr) * A_ + 8 * lg;
        qf[0] = *(const f16x8*)(qp);
        qf[1] = *(const f16x8*)(qp + 32);
    }

    // K staging (pre-swizzled source column); V staging (linear chunks)
    const int row0 = t >> 3;
    const int col0 = (t * 8) & 63;
    const int scol = col0 ^ ((row0 & 7) << 3);
    const uint16_t* kg = kh + (size_t)(bh * S_ + row0) * A_ + scol;
    const uint16_t* vg = vpv + (size_t)bh * (S_ * A_) + t * 8;

    float m = -1.0e30f, l = 0.0f;
    f32x4 oacc[4] = {};

    #define STAGE(buf, kt_) do {                                                              \
        const uint16_t* kp_ = kg + (size_t)(kt_) * (64 * A_);                                 \
        const uint16_t* vp_ = vg + (size_t)(kt_) * 4096;                                      \
        __builtin_amdgcn_global_load_lds(kp_,           &Ks[buf][w * 512],        16, 0, 0);  \
        __builtin_amdgcn_global_load_lds(kp_ + 32 * A_, &Ks[buf][2048 + w * 512], 16, 0, 0);  \
        __builtin_amdgcn_global_load_lds(vp_,           &Vs[buf][w * 512],        16, 0, 0);  \
        __builtin_amdgcn_global_load_lds(vp_ + 2048,    &Vs[buf][2048 + w * 512], 16, 0, 0);  \
    } while (0)

    STAGE(0, 0);
    __syncthreads();

    for (int kt = 0; kt < S_ / 64; kt++) {
        const int cur = kt & 1;
        if (kt + 1 < S_ / 64) STAGE(cur ^ 1, kt + 1);

        // QK^T swapped: sacc[nb] = C[kv = nb*16 + 4*lg + r][q = lr] (log2 domain)
        f32x4 sacc[4] = {};
        #pragma unroll
        for (int kb2 = 0; kb2 < 2; kb2++) {
            #pragma unroll
            for (int nb = 0; nb < 4; nb++) {
                f16x8 kf = *(const f16x8*)(&Ks[cur][0] + swz(nb * 16 + lr, kb2 * 32 + 8 * lg));
                sacc[nb] = __builtin_amdgcn_mfma_f32_16x16x32_f16(kf, qf[kb2], sacc[nb], 0, 0, 0);
            }
        }

        // tile max of row lr: in-lane tree over 16 + 2 cross-lg shuffles
        float t0 = fmaxf(fmaxf(sacc[0][0], sacc[0][1]), fmaxf(sacc[0][2], sacc[0][3]));
        float t1 = fmaxf(fmaxf(sacc[1][0], sacc[1][1]), fmaxf(sacc[1][2], sacc[1][3]));
        float t2 = fmaxf(fmaxf(sacc[2][0], sacc[2][1]), fmaxf(sacc[2][2], sacc[2][3]));
        float t3 = fmaxf(fmaxf(sacc[3][0], sacc[3][1]), fmaxf(sacc[3][2], sacc[3][3]));
        float tm = fmaxf(fmaxf(t0, t1), fmaxf(t2, t3));
        tm = fmaxf(tm, __shfl_xor(tm, 16));
        tm = fmaxf(tm, __shfl_xor(tm, 32));

        // defer-max: P bounded by 2^11 = 2048 < f16 max
        if (__any(tm > m + 11.0f)) {
            float mn = fmaxf(m, tm);
            float sc = exp2f_fast(m - mn);
            l *= sc;
            m = mn;
            float scr[4];
            #pragma unroll
            for (int r = 0; r < 4; r++) scr[r] = __shfl(sc, 4 * lg + r);
            #pragma unroll
            for (int nb = 0; nb < 4; nb++) {
                #pragma unroll
                for (int r = 0; r < 4; r++) oacc[nb][r] *= scr[r];
            }
        }

        // P = exp2(s - m) packed directly into PV A-fragments (shared permutation pi)
        f16x8 paf[2];
        #pragma unroll
        for (int kb2 = 0; kb2 < 2; kb2++) {
            #pragma unroll
            for (int jh = 0; jh < 2; jh++) {
                #pragma unroll
                for (int r = 0; r < 4; r++) {
                    float e = exp2f_fast(sacc[2 * kb2 + jh][r] - m);
                    l += e;
                    paf[kb2][jh * 4 + r] = (_Float16)e;
                }
            }
        }

        // PV: B-fragment chunks are linear, conflict-free b128 reads
        #pragma unroll
        for (int kb2 = 0; kb2 < 2; kb2++) {
            #pragma unroll
            for (int nb = 0; nb < 4; nb++) {
                f16x8 vf = *(const f16x8*)(&Vs[cur][0] + ((kb2 * 4 + lg) * 64 + nb * 16 + lr) * 8);
                oacc[nb] = __builtin_amdgcn_mfma_f32_16x16x32_f16(paf[kb2], vf, oacc[nb], 0, 0, 0);
            }
        }
        __syncthreads();   // drains vmcnt (next buf ready) + all waves done with cur buf
    }
    #undef STAGE

    // full row sums, redistribute to oacc rows, normalize + store
    l += __shfl_xor(l, 16);
    l += __shfl_xor(l, 32);
    float invl[4];
    #pragma unroll
    for (int r = 0; r < 4; r++) invl[r] = 1.0f / __shfl(l, 4 * lg + r);
    #pragma unroll
    for (int r = 0; r < 4; r++) {
        const int s = qt * 64 + w * 16 + 4 * lg + r;
        #pragma unroll
        for (int nb = 0; nb < 4; nb++) {
            const int a = nb * 16 + lr;
            out[(size_t)(b * S_ + s) * (H_ * A_) + h * A_ + a] = oacc[nb][r] * invl[r];
        }
    }
}

// ----------------------------------------------------------------
extern "C" void kernel_launch(void* const* d_in, const int* in_sizes, int n_in,
                              void* d_out, int out_size, void* d_ws, size_t ws_size,
                              hipStream_t stream)
{
    const float* q  = (const float*)d_in[0];
    const float* k  = (const float*)d_in[1];
    const float* v  = (const float*)d_in[2];
    const float* Wq = (const float*)d_in[3];
    const float* bq = (const float*)d_in[4];
    const float* Wk = (const float*)d_in[5];
    const float* bk = (const float*)d_in[6];
    const float* Wv = (const float*)d_in[7];
    const float* bv = (const float*)d_in[8];
    float* out = (float*)d_out;

    uint8_t* ws = (uint8_t*)d_ws;
    const size_t SZ_H  = (size_t)BH_ * S_ * A_ * 2;     // 16 MB each
    const size_t SZ_WT = (size_t)3 * H_ * A_ * D_ * 2;  // 6 MB
    const size_t SZ_AB = (size_t)M_ * D_ * 2;           // 16 MB each
    uint16_t* qh  = (uint16_t*)(ws);
    uint16_t* kh  = (uint16_t*)(ws + SZ_H);
    uint16_t* vpv = (uint16_t*)(ws + 2 * SZ_H);
    uint16_t* Wt  = (uint16_t*)(ws + 3 * SZ_H);
    uint16_t* qb  = (uint16_t*)(ws + 3 * SZ_H + SZ_WT);
    uint16_t* kb  = (uint16_t*)(ws + 3 * SZ_H + SZ_WT + SZ_AB);
    uint16_t* vb  = (uint16_t*)(ws + 3 * SZ_H + SZ_WT + 2 * SZ_AB);
    const int preconv = (ws_size >= 3 * SZ_H + SZ_WT + 3 * SZ_AB) ? 1 : 0;

    prep_w<<<dim3(16, H_, 3), 256, 0, stream>>>(Wq, Wk, Wv, Wt);
    if (preconv)
        prep_qkv<<<dim3(3 * M_ * D_ / 8 / 256), 256, 0, stream>>>(q, k, v, qb, kb, vb);
    proj_kernel<<<dim3(H_, M_ / 128, 3), 256, 0, stream>>>(q, k, v, qb, kb, vb, Wt,
                                                           bq, bk, bv, qh, kh, vpv, preconv);
    flash_kernel<<<dim3(S_ / 64, BH_), 256, 0, stream>>>(qh, kh, vpv, out);
}

// Round 6
// 219.069 us; speedup vs baseline: 1.6240x; 1.1222x over previous
//
#include <hip/hip_runtime.h>
#include <stdint.h>

#define B_ 4
#define S_ 2048
#define D_ 1024
#define H_ 16
#define A_ 64
#define M_ (B_*S_)    // 8192
#define BH_ (B_*H_)   // 64
#define INV_LN2 1.4426950408889634f

typedef _Float16 f16x8 __attribute__((ext_vector_type(8)));
typedef _Float16 f16x2 __attribute__((ext_vector_type(2)));
typedef float    f32x4 __attribute__((ext_vector_type(4)));

__device__ __forceinline__ uint32_t f2h(float f) {
    _Float16 h = (_Float16)f;                      // RNE
    return (uint32_t)__builtin_bit_cast(uint16_t, h);
}

__device__ __forceinline__ float exp2f_fast(float x) {
    return __builtin_amdgcn_exp2f(x);              // v_exp_f32: computes 2^x
}

__device__ __forceinline__ uint32_t pkrtz(float a, float b) {
    return __builtin_bit_cast(uint32_t, __builtin_amdgcn_cvt_pkrtz(a, b));
}

// XOR swizzle for [R][64]-f16 LDS tiles (row stride 128 B)
__device__ __forceinline__ int swz(int row, int col) {
    return (row * 64 + col) ^ ((row & 7) << 3);
}

// ---------------------------------------------------------------- prep: W -> Wt[p][h][a][d] f16
// p==0 (Wq) additionally scaled by 1/ln2 so QK^T scores land in log2 domain.
__global__ __launch_bounds__(256) void prep_w(
    const float* __restrict__ Wq, const float* __restrict__ Wk, const float* __restrict__ Wv,
    uint16_t* __restrict__ Wt)
{
    __shared__ float tile[64][65];
    const int dt = blockIdx.x, h = blockIdx.y, p = blockIdx.z;
    const float* W = (p == 0) ? Wq : (p == 1) ? Wk : Wv;
    const float sc = (p == 0) ? INV_LN2 : 1.0f;
    const float* src = W + (h * D_ + dt * 64) * A_;   // [64 d][64 a]
    const int t = threadIdx.x;
    const int r0 = t >> 4, c4 = (t & 15) * 4;
    #pragma unroll
    for (int i = 0; i < 4; i++) {
        int r = r0 + i * 16;
        float4 x = *(const float4*)(src + r * A_ + c4);
        tile[r][c4] = x.x; tile[r][c4 + 1] = x.y; tile[r][c4 + 2] = x.z; tile[r][c4 + 3] = x.w;
    }
    __syncthreads();
    uint16_t* dst = Wt + (p * H_ + h) * (A_ * D_) + dt * 64;
    #pragma unroll
    for (int i = 0; i < 4; i++) {
        int a = r0 + i * 16;
        int d4 = (t & 15) * 4;
        uint2 o2;
        o2.x = f2h(tile[d4][a] * sc)     | (f2h(tile[d4 + 1][a] * sc) << 16);
        o2.y = f2h(tile[d4 + 2][a] * sc) | (f2h(tile[d4 + 3][a] * sc) << 16);
        *(uint2*)(dst + a * D_ + d4) = o2;
    }
}

// ---------------------------------------------------------------- prep: q/k/v f32 -> f16
__global__ __launch_bounds__(256) void prep_qkv(
    const float* __restrict__ q, const float* __restrict__ k, const float* __restrict__ v,
    uint16_t* __restrict__ qb, uint16_t* __restrict__ kb, uint16_t* __restrict__ vb)
{
    const int gi = blockIdx.x * 256 + threadIdx.x;
    const int NT = M_ * D_ / 8;
    const float* src; uint16_t* dst; int idx;
    if (gi < NT)          { src = q; dst = qb; idx = gi; }
    else if (gi < 2 * NT) { src = k; dst = kb; idx = gi - NT; }
    else                  { src = v; dst = vb; idx = gi - 2 * NT; }
    const int off = idx * 8;
    float4 x0 = *(const float4*)(src + off);
    float4 x1 = *(const float4*)(src + off + 4);
    uint4 o;
    o.x = f2h(x0.x) | (f2h(x0.y) << 16);
    o.y = f2h(x0.z) | (f2h(x0.w) << 16);
    o.z = f2h(x1.x) | (f2h(x1.y) << 16);
    o.w = f2h(x1.z) | (f2h(x1.w) << 16);
    *(uint4*)(dst + off) = o;
}

// ---------------------------------------------------------------- projection GEMM
// 512 thr (8 waves, 2x4), tile M=128 x N=256 (4 heads), K-step 64.
// Staging via global_load_lds with pre-swizzled source columns.
// out: p==0/1 -> qh/kh [BH][S][A] f16 (qh pre-scaled by 1/ln2);
//      p==2   -> vpv [BH][32 kt][kb][lg][a][8] f16 chunk layout (PV B-fragments).
__global__ __launch_bounds__(512) void proj_kernel(
    const uint16_t* __restrict__ qb, const uint16_t* __restrict__ kb, const uint16_t* __restrict__ vb,
    const uint16_t* __restrict__ Wt,
    const float* __restrict__ bq, const float* __restrict__ bk, const float* __restrict__ bv,
    uint16_t* __restrict__ qh, uint16_t* __restrict__ kh, uint16_t* __restrict__ vpv)
{
    __shared__ __align__(16) uint16_t As[128 * 64];   // 16 KB
    __shared__ __align__(16) uint16_t Bs[256 * 64];   // 32 KB  rows: h'*64 + a
    const int p = blockIdx.z, nt = blockIdx.y, mt = blockIdx.x;
    const int t = threadIdx.x, lane = t & 63, w = t >> 6;
    const int wr = w >> 2, wc = w & 3;
    const int lr = lane & 15, lg = lane >> 4;
    const int Mbase = mt * 128;
    const uint16_t* Ab = (p == 0) ? qb : (p == 1) ? kb : vb;

    // staging sources: pre-swizzled column (row&7 invariant under +64-row steps)
    const int arow = t >> 3;
    const int acol = (t * 8) & 63;
    const int ascol = acol ^ ((arow & 7) << 3);
    const uint16_t* asrc0 = Ab + (size_t)(Mbase + arow) * D_ + ascol;
    const uint16_t* asrc1 = asrc0 + (size_t)64 * D_;
    const uint16_t* bsrc[4];
    #pragma unroll
    for (int i = 0; i < 4; i++) {
        int row = arow + i * 64;                 // 0..255: h' = row>>6, a = row&63
        bsrc[i] = Wt + ((size_t)(p * H_ + nt * 4 + (row >> 6)) * A_ + (row & 63)) * D_ + ascol;
    }

    f32x4 acc[4][4] = {};

    for (int kk = 0; kk < D_; kk += 64) {
        __builtin_amdgcn_global_load_lds(asrc0 + kk, &As[w * 512],        16, 0, 0);
        __builtin_amdgcn_global_load_lds(asrc1 + kk, &As[4096 + w * 512], 16, 0, 0);
        #pragma unroll
        for (int i = 0; i < 4; i++)
            __builtin_amdgcn_global_load_lds(bsrc[i] + kk, &Bs[i * 4096 + w * 512], 16, 0, 0);
        __syncthreads();   // drains vmcnt: tiles ready
        #pragma unroll
        for (int kb2 = 0; kb2 < 2; kb2++) {
            f16x8 af[4], bf[4];
            #pragma unroll
            for (int mb = 0; mb < 4; mb++)
                af[mb] = *(const f16x8*)(As + swz(wr * 64 + mb * 16 + lr, kb2 * 32 + 8 * lg));
            #pragma unroll
            for (int nb = 0; nb < 4; nb++)
                bf[nb] = *(const f16x8*)(Bs + swz(wc * 64 + nb * 16 + lr, kb2 * 32 + 8 * lg));
            #pragma unroll
            for (int mb = 0; mb < 4; mb++) {
                #pragma unroll
                for (int nb = 0; nb < 4; nb++)
                    acc[mb][nb] = __builtin_amdgcn_mfma_f32_16x16x32_f16(af[mb], bf[nb], acc[mb][nb], 0, 0, 0);
            }
        }
        __syncthreads();   // all waves done reading before next stage
    }

    const int h = nt * 4 + wc;
    const int b = Mbase >> 11;           // S_=2048 rows per batch
    const int bh = b * H_ + h;
    const int sbase = Mbase & (S_ - 1);
    const float* bias = ((p == 0) ? bq : (p == 1) ? bk : bv) + h * A_;
    const float bsc = (p == 0) ? INV_LN2 : 1.0f;
    #pragma unroll
    for (int mb = 0; mb < 4; mb++) {
        #pragma unroll
        for (int nb = 0; nb < 4; nb++) {
            const int a = nb * 16 + lr;
            const float bia = bias[a] * bsc;
            const int s0 = sbase + wr * 64 + mb * 16 + 4 * lg;
            if (p < 2) {
                uint16_t* o = (p == 0) ? qh : kh;
                #pragma unroll
                for (int r = 0; r < 4; r++)
                    o[(bh * S_ + s0 + r) * A_ + a] = (uint16_t)f2h(acc[mb][nb][r] + bia);
            } else {
                // chunk layout: [(bh*32+kt)*512 + kb2*256 + lg2*64 + a] chunks of 8 u16
                const int kt2 = s0 >> 6, kv0 = s0 & 63;
                const int kb2 = kv0 >> 5, jhi = (kv0 >> 4) & 1, lg2 = (kv0 >> 2) & 3;
                uint2 pk2;
                pk2.x = f2h(acc[mb][nb][0] + bia) | (f2h(acc[mb][nb][1] + bia) << 16);
                pk2.y = f2h(acc[mb][nb][2] + bia) | (f2h(acc[mb][nb][3] + bia) << 16);
                *(uint2*)(vpv + ((size_t)((bh * 32 + kt2) * 512 + kb2 * 256 + lg2 * 64 + a)) * 8 + 4 * jhi) = pk2;
            }
        }
    }
}

// ---------------------------------------------------------------- flash attention
// Swapped QK^T (A=K, B=Q): lane owns one q-row; P stays in registers and feeds
// PV's A-fragment directly. l-sum via ones-MFMA (row sums land in oacc layout).
__global__ __launch_bounds__(256) void flash_kernel(
    const uint16_t* __restrict__ qh, const uint16_t* __restrict__ kh,
    const uint16_t* __restrict__ vpv, float* __restrict__ out)
{
    __shared__ __align__(16) uint16_t Ks[2][4096];
    __shared__ __align__(16) uint16_t Vs[2][4096];
    const int t = threadIdx.x, lane = t & 63, w = t >> 6;
    const int lr = lane & 15, lg = lane >> 4;
    const int qt = blockIdx.x, bh = blockIdx.y;
    const int b = bh >> 4, h = bh & (H_ - 1);

    // Q as B-fragment: lane (lr,lg) holds Q[q = w*16+lr][d = kb*32 + 8*lg + j]
    f16x8 qf[2];
    {
        const uint16_t* qp = qh + (size_t)(bh * S_ + qt * 64 + w * 16 + lr) * A_ + 8 * lg;
        qf[0] = *(const f16x8*)(qp);
        qf[1] = *(const f16x8*)(qp + 32);
    }
    f16x8 ones;
    #pragma unroll
    for (int j = 0; j < 8; j++) ones[j] = (_Float16)1.0f;

    // K staging (pre-swizzled source column); V staging (linear chunks)
    const int row0 = t >> 3;
    const int col0 = (t * 8) & 63;
    const int scol = col0 ^ ((row0 & 7) << 3);
    const uint16_t* kg = kh + (size_t)(bh * S_ + row0) * A_ + scol;
    const uint16_t* vg = vpv + (size_t)bh * (S_ * A_) + t * 8;

    float m = -1.0e30f;
    f32x4 oacc[4] = {};
    f32x4 lsum = {};

    #define STAGE(buf, kt_) do {                                                              \
        const uint16_t* kp_ = kg + (size_t)(kt_) * (64 * A_);                                 \
        const uint16_t* vp_ = vg + (size_t)(kt_) * 4096;                                      \
        __builtin_amdgcn_global_load_lds(kp_,           &Ks[buf][w * 512],        16, 0, 0);  \
        __builtin_amdgcn_global_load_lds(kp_ + 32 * A_, &Ks[buf][2048 + w * 512], 16, 0, 0);  \
        __builtin_amdgcn_global_load_lds(vp_,           &Vs[buf][w * 512],        16, 0, 0);  \
        __builtin_amdgcn_global_load_lds(vp_ + 2048,    &Vs[buf][2048 + w * 512], 16, 0, 0);  \
    } while (0)

    STAGE(0, 0);
    __syncthreads();

    for (int kt = 0; kt < S_ / 64; kt++) {
        const int cur = kt & 1;
        if (kt + 1 < S_ / 64) STAGE(cur ^ 1, kt + 1);

        // QK^T swapped: sacc[nb] = C[kv = nb*16 + 4*lg + r][q = lr] (log2 domain)
        f32x4 sacc[4] = {};
        #pragma unroll
        for (int kb2 = 0; kb2 < 2; kb2++) {
            #pragma unroll
            for (int nb = 0; nb < 4; nb++) {
                f16x8 kf = *(const f16x8*)(&Ks[cur][0] + swz(nb * 16 + lr, kb2 * 32 + 8 * lg));
                sacc[nb] = __builtin_amdgcn_mfma_f32_16x16x32_f16(kf, qf[kb2], sacc[nb], 0, 0, 0);
            }
        }

        // tile max of row lr: max3-friendly tree + 2 cross-lg shuffles
        float a0 = fmaxf(fmaxf(sacc[0][0], sacc[0][1]), sacc[0][2]);
        float a1 = fmaxf(fmaxf(sacc[0][3], sacc[1][0]), sacc[1][1]);
        float a2 = fmaxf(fmaxf(sacc[1][2], sacc[1][3]), sacc[2][0]);
        float a3 = fmaxf(fmaxf(sacc[2][1], sacc[2][2]), sacc[2][3]);
        float a4 = fmaxf(fmaxf(sacc[3][0], sacc[3][1]), sacc[3][2]);
        float tm = fmaxf(fmaxf(fmaxf(a0, a1), fmaxf(a2, a3)), fmaxf(a4, sacc[3][3]));
        tm = fmaxf(tm, __shfl_xor(tm, 16));
        tm = fmaxf(tm, __shfl_xor(tm, 32));

        // defer-max: P bounded by 2^11 = 2048 < f16 max
        if (__any(tm > m + 11.0f)) {
            float mn = fmaxf(m, tm);
            float sc = exp2f_fast(m - mn);
            m = mn;
            float scr[4];
            #pragma unroll
            for (int r = 0; r < 4; r++) scr[r] = __shfl(sc, 4 * lg + r);
            #pragma unroll
            for (int r = 0; r < 4; r++) lsum[r] *= scr[r];
            #pragma unroll
            for (int nb = 0; nb < 4; nb++) {
                #pragma unroll
                for (int r = 0; r < 4; r++) oacc[nb][r] *= scr[r];
            }
        }

        // P = exp2(s - m) packed (pkrtz) directly into PV A-fragments
        f16x8 paf[2];
        #pragma unroll
        for (int kb2 = 0; kb2 < 2; kb2++) {
            float e[8];
            #pragma unroll
            for (int jh = 0; jh < 2; jh++) {
                #pragma unroll
                for (int r = 0; r < 4; r++)
                    e[jh * 4 + r] = exp2f_fast(sacc[2 * kb2 + jh][r] - m);
            }
            uint4 u;
            u.x = pkrtz(e[0], e[1]); u.y = pkrtz(e[2], e[3]);
            u.z = pkrtz(e[4], e[5]); u.w = pkrtz(e[6], e[7]);
            paf[kb2] = __builtin_bit_cast(f16x8, u);
        }

        // l-sum via ones-MFMA: row sums land in oacc row layout (row = 4*lg+r)
        lsum = __builtin_amdgcn_mfma_f32_16x16x32_f16(paf[0], ones, lsum, 0, 0, 0);
        lsum = __builtin_amdgcn_mfma_f32_16x16x32_f16(paf[1], ones, lsum, 0, 0, 0);

        // PV: B-fragment chunks are linear, conflict-free b128 reads
        #pragma unroll
        for (int kb2 = 0; kb2 < 2; kb2++) {
            #pragma unroll
            for (int nb = 0; nb < 4; nb++) {
                f16x8 vf = *(const f16x8*)(&Vs[cur][0] + ((kb2 * 4 + lg) * 64 + nb * 16 + lr) * 8);
                oacc[nb] = __builtin_amdgcn_mfma_f32_16x16x32_f16(paf[kb2], vf, oacc[nb], 0, 0, 0);
            }
        }
        __syncthreads();   // drains vmcnt (next buf ready) + all waves done with cur buf
    }
    #undef STAGE

    // normalize + store (lsum already in oacc row layout — no shuffles needed)
    #pragma unroll
    for (int r = 0; r < 4; r++) {
        const float inv = 1.0f / lsum[r];
        const int s = qt * 64 + w * 16 + 4 * lg + r;
        #pragma unroll
        for (int nb = 0; nb < 4; nb++) {
            const int a = nb * 16 + lr;
            out[(size_t)(b * S_ + s) * (H_ * A_) + h * A_ + a] = oacc[nb][r] * inv;
        }
    }
}

// ----------------------------------------------------------------
extern "C" void kernel_launch(void* const* d_in, const int* in_sizes, int n_in,
                              void* d_out, int out_size, void* d_ws, size_t ws_size,
                              hipStream_t stream)
{
    const float* q  = (const float*)d_in[0];
    const float* k  = (const float*)d_in[1];
    const float* v  = (const float*)d_in[2];
    const float* Wq = (const float*)d_in[3];
    const float* bq = (const float*)d_in[4];
    const float* Wk = (const float*)d_in[5];
    const float* bk = (const float*)d_in[6];
    const float* Wv = (const float*)d_in[7];
    const float* bv = (const float*)d_in[8];
    float* out = (float*)d_out;

    uint8_t* ws = (uint8_t*)d_ws;
    const size_t SZ_H  = (size_t)BH_ * S_ * A_ * 2;     // 16 MB each
    const size_t SZ_WT = (size_t)3 * H_ * A_ * D_ * 2;  // 6 MB
    const size_t SZ_AB = (size_t)M_ * D_ * 2;           // 16 MB each
    uint16_t* qh  = (uint16_t*)(ws);
    uint16_t* kh  = (uint16_t*)(ws + SZ_H);
    uint16_t* vpv = (uint16_t*)(ws + 2 * SZ_H);
    uint16_t* Wt  = (uint16_t*)(ws + 3 * SZ_H);
    uint16_t* qb  = (uint16_t*)(ws + 3 * SZ_H + SZ_WT);
    uint16_t* kb  = (uint16_t*)(ws + 3 * SZ_H + SZ_WT + SZ_AB);
    uint16_t* vb  = (uint16_t*)(ws + 3 * SZ_H + SZ_WT + 2 * SZ_AB);

    prep_w<<<dim3(16, H_, 3), 256, 0, stream>>>(Wq, Wk, Wv, Wt);
    prep_qkv<<<dim3(3 * M_ * D_ / 8 / 256), 256, 0, stream>>>(q, k, v, qb, kb, vb);
    proj_kernel<<<dim3(M_ / 128, 4, 3), 512, 0, stream>>>(qb, kb, vb, Wt,
                                                          bq, bk, bv, qh, kh, vpv);
    flash_kernel<<<dim3(S_ / 64, BH_), 256, 0, stream>>>(qh, kh, vpv, out);
}

// Round 7
// 218.804 us; speedup vs baseline: 1.6260x; 1.0012x over previous
//
#include <hip/hip_runtime.h>
#include <stdint.h>

#define B_ 4
#define S_ 2048
#define D_ 1024
#define H_ 16
#define A_ 64
#define M_ (B_*S_)    // 8192
#define BH_ (B_*H_)   // 64
#define INV_LN2 1.4426950408889634f

typedef _Float16 f16x8 __attribute__((ext_vector_type(8)));
typedef float    f32x4 __attribute__((ext_vector_type(4)));

__device__ __forceinline__ uint32_t f2h(float f) {
    _Float16 h = (_Float16)f;                      // RNE
    return (uint32_t)__builtin_bit_cast(uint16_t, h);
}

__device__ __forceinline__ float exp2f_fast(float x) {
    return __builtin_amdgcn_exp2f(x);              // v_exp_f32: computes 2^x
}

__device__ __forceinline__ uint32_t pkrtz(float a, float b) {
    return __builtin_bit_cast(uint32_t, __builtin_amdgcn_cvt_pkrtz(a, b));
}

// XOR swizzle for [R][64]-f16 LDS tiles (row stride 128 B)
__device__ __forceinline__ int swz(int row, int col) {
    return (row * 64 + col) ^ ((row & 7) << 3);
}

// ---------------------------------------------------------------- prep: W -> Wt[p][h][a][d] f16
// p==0 (Wq) additionally scaled by 1/ln2 so QK^T scores land in log2 domain.
__global__ __launch_bounds__(256) void prep_w(
    const float* __restrict__ Wq, const float* __restrict__ Wk, const float* __restrict__ Wv,
    uint16_t* __restrict__ Wt)
{
    __shared__ float tile[64][65];
    const int dt = blockIdx.x, h = blockIdx.y, p = blockIdx.z;
    const float* W = (p == 0) ? Wq : (p == 1) ? Wk : Wv;
    const float sc = (p == 0) ? INV_LN2 : 1.0f;
    const float* src = W + (h * D_ + dt * 64) * A_;   // [64 d][64 a]
    const int t = threadIdx.x;
    const int r0 = t >> 4, c4 = (t & 15) * 4;
    #pragma unroll
    for (int i = 0; i < 4; i++) {
        int r = r0 + i * 16;
        float4 x = *(const float4*)(src + r * A_ + c4);
        tile[r][c4] = x.x; tile[r][c4 + 1] = x.y; tile[r][c4 + 2] = x.z; tile[r][c4 + 3] = x.w;
    }
    __syncthreads();
    uint16_t* dst = Wt + (p * H_ + h) * (A_ * D_) + dt * 64;
    #pragma unroll
    for (int i = 0; i < 4; i++) {
        int a = r0 + i * 16;
        int d4 = (t & 15) * 4;
        uint2 o2;
        o2.x = f2h(tile[d4][a] * sc)     | (f2h(tile[d4 + 1][a] * sc) << 16);
        o2.y = f2h(tile[d4 + 2][a] * sc) | (f2h(tile[d4 + 3][a] * sc) << 16);
        *(uint2*)(dst + a * D_ + d4) = o2;
    }
}

// ---------------------------------------------------------------- prep: q/k/v f32 -> f16
__global__ __launch_bounds__(256) void prep_qkv(
    const float* __restrict__ q, const float* __restrict__ k, const float* __restrict__ v,
    uint16_t* __restrict__ qb, uint16_t* __restrict__ kb, uint16_t* __restrict__ vb)
{
    const int gi = blockIdx.x * 256 + threadIdx.x;
    const int NT = M_ * D_ / 8;
    const float* src; uint16_t* dst; int idx;
    if (gi < NT)          { src = q; dst = qb; idx = gi; }
    else if (gi < 2 * NT) { src = k; dst = kb; idx = gi - NT; }
    else                  { src = v; dst = vb; idx = gi - 2 * NT; }
    const int off = idx * 8;
    float4 x0 = *(const float4*)(src + off);
    float4 x1 = *(const float4*)(src + off + 4);
    uint4 o;
    o.x = f2h(x0.x) | (f2h(x0.y) << 16);
    o.y = f2h(x0.z) | (f2h(x0.w) << 16);
    o.z = f2h(x1.x) | (f2h(x1.y) << 16);
    o.w = f2h(x1.z) | (f2h(x1.w) << 16);
    *(uint4*)(dst + off) = o;
}

// ---------------------------------------------------------------- projection GEMM
// 512 thr (8 waves, 2x4), tile M=128 x N=256 (4 heads), K-step 64.
// Staging via global_load_lds with pre-swizzled source columns.
// out: p==0/1 -> qh/kh [BH][S][A] f16 (qh pre-scaled by 1/ln2);
//      p==2   -> vpv [BH][32 kt][kb][lg][a][8] f16 chunk layout (PV B-fragments).
__global__ __launch_bounds__(512) void proj_kernel(
    const uint16_t* __restrict__ qb, const uint16_t* __restrict__ kb, const uint16_t* __restrict__ vb,
    const uint16_t* __restrict__ Wt,
    const float* __restrict__ bq, const float* __restrict__ bk, const float* __restrict__ bv,
    uint16_t* __restrict__ qh, uint16_t* __restrict__ kh, uint16_t* __restrict__ vpv)
{
    __shared__ __align__(16) uint16_t As[128 * 64];   // 16 KB
    __shared__ __align__(16) uint16_t Bs[256 * 64];   // 32 KB  rows: h'*64 + a
    const int p = blockIdx.z, nt = blockIdx.y, mt = blockIdx.x;
    const int t = threadIdx.x, lane = t & 63, w = t >> 6;
    const int wr = w >> 2, wc = w & 3;
    const int lr = lane & 15, lg = lane >> 4;
    const int Mbase = mt * 128;
    const uint16_t* Ab = (p == 0) ? qb : (p == 1) ? kb : vb;

    // staging sources: pre-swizzled column (row&7 invariant under +64-row steps)
    const int arow = t >> 3;
    const int acol = (t * 8) & 63;
    const int ascol = acol ^ ((arow & 7) << 3);
    const uint16_t* asrc0 = Ab + (size_t)(Mbase + arow) * D_ + ascol;
    const uint16_t* asrc1 = asrc0 + (size_t)64 * D_;
    const uint16_t* bsrc[4];
    #pragma unroll
    for (int i = 0; i < 4; i++) {
        int row = arow + i * 64;                 // 0..255: h' = row>>6, a = row&63
        bsrc[i] = Wt + ((size_t)(p * H_ + nt * 4 + (row >> 6)) * A_ + (row & 63)) * D_ + ascol;
    }

    f32x4 acc[4][4] = {};

    for (int kk = 0; kk < D_; kk += 64) {
        __builtin_amdgcn_global_load_lds(asrc0 + kk, &As[w * 512],        16, 0, 0);
        __builtin_amdgcn_global_load_lds(asrc1 + kk, &As[4096 + w * 512], 16, 0, 0);
        #pragma unroll
        for (int i = 0; i < 4; i++)
            __builtin_amdgcn_global_load_lds(bsrc[i] + kk, &Bs[i * 4096 + w * 512], 16, 0, 0);
        __syncthreads();   // drains vmcnt: tiles ready
        #pragma unroll
        for (int kb2 = 0; kb2 < 2; kb2++) {
            f16x8 af[4], bf[4];
            #pragma unroll
            for (int mb = 0; mb < 4; mb++)
                af[mb] = *(const f16x8*)(As + swz(wr * 64 + mb * 16 + lr, kb2 * 32 + 8 * lg));
            #pragma unroll
            for (int nb = 0; nb < 4; nb++)
                bf[nb] = *(const f16x8*)(Bs + swz(wc * 64 + nb * 16 + lr, kb2 * 32 + 8 * lg));
            #pragma unroll
            for (int mb = 0; mb < 4; mb++) {
                #pragma unroll
                for (int nb = 0; nb < 4; nb++)
                    acc[mb][nb] = __builtin_amdgcn_mfma_f32_16x16x32_f16(af[mb], bf[nb], acc[mb][nb], 0, 0, 0);
            }
        }
        __syncthreads();   // all waves done reading before next stage
    }

    const int h = nt * 4 + wc;
    const int b = Mbase >> 11;           // S_=2048 rows per batch
    const int bh = b * H_ + h;
    const int sbase = Mbase & (S_ - 1);
    const float* bias = ((p == 0) ? bq : (p == 1) ? bk : bv) + h * A_;
    const float bsc = (p == 0) ? INV_LN2 : 1.0f;
    #pragma unroll
    for (int mb = 0; mb < 4; mb++) {
        #pragma unroll
        for (int nb = 0; nb < 4; nb++) {
            const int a = nb * 16 + lr;
            const float bia = bias[a] * bsc;
            const int s0 = sbase + wr * 64 + mb * 16 + 4 * lg;
            if (p < 2) {
                uint16_t* o = (p == 0) ? qh : kh;
                #pragma unroll
                for (int r = 0; r < 4; r++)
                    o[(bh * S_ + s0 + r) * A_ + a] = (uint16_t)f2h(acc[mb][nb][r] + bia);
            } else {
                // chunk layout: [(bh*32+kt)*512 + kb2*256 + lg2*64 + a] chunks of 8 u16
                const int kt2 = s0 >> 6, kv0 = s0 & 63;
                const int kb2 = kv0 >> 5, jhi = (kv0 >> 4) & 1, lg2 = (kv0 >> 2) & 3;
                uint2 pk2;
                pk2.x = f2h(acc[mb][nb][0] + bia) | (f2h(acc[mb][nb][1] + bia) << 16);
                pk2.y = f2h(acc[mb][nb][2] + bia) | (f2h(acc[mb][nb][3] + bia) << 16);
                *(uint2*)(vpv + ((size_t)((bh * 32 + kt2) * 512 + kb2 * 256 + lg2 * 64 + a)) * 8 + 4 * jhi) = pk2;
            }
        }
    }
}

// ---------------------------------------------------------------- flash attention
// Swapped QK^T (A=K, B=Q): lane owns one q-row; P stays in registers and feeds
// PV's A-fragment directly. Running max m folded into QK's C-init (sacc = s - m,
// zero subtracts in steady state). l-sum via ones-MFMA.
__global__ __launch_bounds__(256) void flash_kernel(
    const uint16_t* __restrict__ qh, const uint16_t* __restrict__ kh,
    const uint16_t* __restrict__ vpv, float* __restrict__ out)
{
    __shared__ __align__(16) uint16_t Ks[2][4096];
    __shared__ __align__(16) uint16_t Vs[2][4096];
    const int t = threadIdx.x, lane = t & 63, w = t >> 6;
    const int lr = lane & 15, lg = lane >> 4;
    const int qt = blockIdx.x, bh = blockIdx.y;
    const int b = bh >> 4, h = bh & (H_ - 1);

    // Q as B-fragment: lane (lr,lg) holds Q[q = w*16+lr][d = kb*32 + 8*lg + j]
    f16x8 qf[2];
    {
        const uint16_t* qp = qh + (size_t)(bh * S_ + qt * 64 + w * 16 + lr) * A_ + 8 * lg;
        qf[0] = *(const f16x8*)(qp);
        qf[1] = *(const f16x8*)(qp + 32);
    }
    f16x8 ones;
    #pragma unroll
    for (int j = 0; j < 8; j++) ones[j] = (_Float16)1.0f;

    // K staging (pre-swizzled source column); V staging (linear chunks)
    const int row0 = t >> 3;
    const int col0 = (t * 8) & 63;
    const int scol = col0 ^ ((row0 & 7) << 3);
    const uint16_t* kg = kh + (size_t)(bh * S_ + row0) * A_ + scol;
    const uint16_t* vg = vpv + (size_t)bh * (S_ * A_) + t * 8;

    // m = running max of q-row lr (log2 domain). Init 0 (scores are O(±50);
    // P=2^s stays finite in f32 until the first rescale, which triggers on the
    // first tile whose max exceeds 11).
    float m = 0.0f;
    f32x4 oacc[4] = {};
    f32x4 lsum = {};

    #define STAGE(buf, kt_) do {                                                              \
        const uint16_t* kp_ = kg + (size_t)(kt_) * (64 * A_);                                 \
        const uint16_t* vp_ = vg + (size_t)(kt_) * 4096;                                      \
        __builtin_amdgcn_global_load_lds(kp_,           &Ks[buf][w * 512],        16, 0, 0);  \
        __builtin_amdgcn_global_load_lds(kp_ + 32 * A_, &Ks[buf][2048 + w * 512], 16, 0, 0);  \
        __builtin_amdgcn_global_load_lds(vp_,           &Vs[buf][w * 512],        16, 0, 0);  \
        __builtin_amdgcn_global_load_lds(vp_ + 2048,    &Vs[buf][2048 + w * 512], 16, 0, 0);  \
    } while (0)

    STAGE(0, 0);
    __syncthreads();

    for (int kt = 0; kt < S_ / 64; kt++) {
        const int cur = kt & 1;
        if (kt + 1 < S_ / 64) STAGE(cur ^ 1, kt + 1);

        // QK^T swapped, C-init = -m: sacc[nb] = s(kv = nb*16+4*lg+r, q = lr) - m
        const float negm = -m;
        f32x4 minit = {negm, negm, negm, negm};
        f32x4 sacc[4] = {minit, minit, minit, minit};
        __builtin_amdgcn_s_setprio(1);
        #pragma unroll
        for (int kb2 = 0; kb2 < 2; kb2++) {
            #pragma unroll
            for (int nb = 0; nb < 4; nb++) {
                f16x8 kf = *(const f16x8*)(&Ks[cur][0] + swz(nb * 16 + lr, kb2 * 32 + 8 * lg));
                sacc[nb] = __builtin_amdgcn_mfma_f32_16x16x32_f16(kf, qf[kb2], sacc[nb], 0, 0, 0);
            }
        }
        __builtin_amdgcn_s_setprio(0);

        // tile max (relative to m) of row lr: max3 tree + 2 cross-lg shuffles
        float a0 = fmaxf(fmaxf(sacc[0][0], sacc[0][1]), sacc[0][2]);
        float a1 = fmaxf(fmaxf(sacc[0][3], sacc[1][0]), sacc[1][1]);
        float a2 = fmaxf(fmaxf(sacc[1][2], sacc[1][3]), sacc[2][0]);
        float a3 = fmaxf(fmaxf(sacc[2][1], sacc[2][2]), sacc[2][3]);
        float a4 = fmaxf(fmaxf(sacc[3][0], sacc[3][1]), sacc[3][2]);
        float tm = fmaxf(fmaxf(fmaxf(a0, a1), fmaxf(a2, a3)), fmaxf(a4, sacc[3][3]));
        tm = fmaxf(tm, __shfl_xor(tm, 16));
        tm = fmaxf(tm, __shfl_xor(tm, 32));

        // defer-max: rescale only when some row grew past m+11 (P <= 2^11 < f16 max)
        if (__any(tm > 11.0f)) {
            float delta = fmaxf(tm, 0.0f);
            float sc = exp2f_fast(-delta);
            m += delta;
            #pragma unroll
            for (int nb = 0; nb < 4; nb++) {
                #pragma unroll
                for (int r = 0; r < 4; r++) sacc[nb][r] -= delta;
            }
            float scr[4];
            #pragma unroll
            for (int r = 0; r < 4; r++) scr[r] = __shfl(sc, 4 * lg + r);
            #pragma unroll
            for (int r = 0; r < 4; r++) lsum[r] *= scr[r];
            #pragma unroll
            for (int nb = 0; nb < 4; nb++) {
                #pragma unroll
                for (int r = 0; r < 4; r++) oacc[nb][r] *= scr[r];
            }
        }

        // P = exp2(sacc) packed (pkrtz) directly into PV A-fragments
        f16x8 paf[2];
        #pragma unroll
        for (int kb2 = 0; kb2 < 2; kb2++) {
            float e[8];
            #pragma unroll
            for (int jh = 0; jh < 2; jh++) {
                #pragma unroll
                for (int r = 0; r < 4; r++)
                    e[jh * 4 + r] = exp2f_fast(sacc[2 * kb2 + jh][r]);
            }
            uint4 u;
            u.x = pkrtz(e[0], e[1]); u.y = pkrtz(e[2], e[3]);
            u.z = pkrtz(e[4], e[5]); u.w = pkrtz(e[6], e[7]);
            paf[kb2] = __builtin_bit_cast(f16x8, u);
        }

        // l-sum via ones-MFMA (row sums land in oacc row layout) + PV
        __builtin_amdgcn_s_setprio(1);
        lsum = __builtin_amdgcn_mfma_f32_16x16x32_f16(paf[0], ones, lsum, 0, 0, 0);
        lsum = __builtin_amdgcn_mfma_f32_16x16x32_f16(paf[1], ones, lsum, 0, 0, 0);
        #pragma unroll
        for (int kb2 = 0; kb2 < 2; kb2++) {
            #pragma unroll
            for (int nb = 0; nb < 4; nb++) {
                f16x8 vf = *(const f16x8*)(&Vs[cur][0] + ((kb2 * 4 + lg) * 64 + nb * 16 + lr) * 8);
                oacc[nb] = __builtin_amdgcn_mfma_f32_16x16x32_f16(paf[kb2], vf, oacc[nb], 0, 0, 0);
            }
        }
        __builtin_amdgcn_s_setprio(0);
        __syncthreads();   // drains vmcnt (next buf ready) + all waves done with cur buf
    }
    #undef STAGE

    // normalize + store (lsum already in oacc row layout — no shuffles needed)
    #pragma unroll
    for (int r = 0; r < 4; r++) {
        const float inv = 1.0f / lsum[r];
        const int s = qt * 64 + w * 16 + 4 * lg + r;
        #pragma unroll
        for (int nb = 0; nb < 4; nb++) {
            const int a = nb * 16 + lr;
            out[(size_t)(b * S_ + s) * (H_ * A_) + h * A_ + a] = oacc[nb][r] * inv;
        }
    }
}

// ----------------------------------------------------------------
extern "C" void kernel_launch(void* const* d_in, const int* in_sizes, int n_in,
                              void* d_out, int out_size, void* d_ws, size_t ws_size,
                              hipStream_t stream)
{
    const float* q  = (const float*)d_in[0];
    const float* k  = (const float*)d_in[1];
    const float* v  = (const float*)d_in[2];
    const float* Wq = (const float*)d_in[3];
    const float* bq = (const float*)d_in[4];
    const float* Wk = (const float*)d_in[5];
    const float* bk = (const float*)d_in[6];
    const float* Wv = (const float*)d_in[7];
    const float* bv = (const float*)d_in[8];
    float* out = (float*)d_out;

    uint8_t* ws = (uint8_t*)d_ws;
    const size_t SZ_H  = (size_t)BH_ * S_ * A_ * 2;     // 16 MB each
    const size_t SZ_WT = (size_t)3 * H_ * A_ * D_ * 2;  // 6 MB
    const size_t SZ_AB = (size_t)M_ * D_ * 2;           // 16 MB each
    uint16_t* qh  = (uint16_t*)(ws);
    uint16_t* kh  = (uint16_t*)(ws + SZ_H);
    uint16_t* vpv = (uint16_t*)(ws + 2 * SZ_H);
    uint16_t* Wt  = (uint16_t*)(ws + 3 * SZ_H);
    uint16_t* qb  = (uint16_t*)(ws + 3 * SZ_H + SZ_WT);
    uint16_t* kb  = (uint16_t*)(ws + 3 * SZ_H + SZ_WT + SZ_AB);
    uint16_t* vb  = (uint16_t*)(ws + 3 * SZ_H + SZ_WT + 2 * SZ_AB);

    prep_w<<<dim3(16, H_, 3), 256, 0, stream>>>(Wq, Wk, Wv, Wt);
    prep_qkv<<<dim3(3 * M_ * D_ / 8 / 256), 256, 0, stream>>>(q, k, v, qb, kb, vb);
    proj_kernel<<<dim3(M_ / 128, 4, 3), 512, 0, stream>>>(qb, kb, vb, Wt,
                                                          bq, bk, bv, qh, kh, vpv);
    flash_kernel<<<dim3(S_ / 64, BH_), 256, 0, stream>>>(qh, kh, vpv, out);
}